// Round 1
// baseline (1324.609 us; speedup 1.0000x reference)
//
#include <hip/hip_runtime.h>
#include <math.h>

// ---------- problem constants ----------
#define BB  2
#define TT  2048
#define CC  1024
#define HH  16
#define DHD 64
#define MM  (BB*TT)        // 4096 rows

typedef unsigned short u16;
typedef __bf16 bf16t;
typedef bf16t bf16x8 __attribute__((ext_vector_type(8)));
typedef float f32x4 __attribute__((ext_vector_type(4)));

__device__ __forceinline__ u16 f2bf(float f) {
    union { float f; unsigned int u; } v; v.f = f;
    unsigned int r = v.u + 0x7fffu + ((v.u >> 16) & 1u);
    return (u16)(r >> 16);
}

__device__ __forceinline__ f32x4 mfma16(bf16x8 a, bf16x8 b, f32x4 c) {
    return __builtin_amdgcn_mfma_f32_16x16x32_bf16(a, b, c, 0, 0, 0);
}

// ---------- transpose + cast f32[R][Cc] -> bf16[Cc][R] ----------
__global__ __launch_bounds__(256)
void transpose_cast(const float* __restrict__ in, u16* __restrict__ out, int R, int Cc) {
    __shared__ float tile[32][33];
    int tx = threadIdx.x, ty = threadIdx.y;
    int c0 = blockIdx.x * 32, r0 = blockIdx.y * 32;
    #pragma unroll
    for (int k = 0; k < 4; k++)
        tile[ty + 8*k][tx] = in[(size_t)(r0 + ty + 8*k) * Cc + c0 + tx];
    __syncthreads();
    #pragma unroll
    for (int k = 0; k < 4; k++)
        out[(size_t)(c0 + ty + 8*k) * R + r0 + tx] = f2bf(tile[tx][ty + 8*k]);
}

// ---------- LayerNorm: f32[rows][1024] -> bf16[rows][1024] ----------
__global__ __launch_bounds__(256)
void ln_kernel(const float* __restrict__ x, const float* __restrict__ g,
               const float* __restrict__ bta, u16* __restrict__ out) {
    const int row = blockIdx.x;
    const int tid = threadIdx.x;
    const float* xr = x + (size_t)row * CC;
    float4 v = *(const float4*)(xr + tid * 4);
    float s  = v.x + v.y + v.z + v.w;
    float s2 = v.x*v.x + v.y*v.y + v.z*v.z + v.w*v.w;
    for (int o = 32; o > 0; o >>= 1) {
        s  += __shfl_down(s,  o, 64);
        s2 += __shfl_down(s2, o, 64);
    }
    __shared__ float ps[4], ps2[4];
    __shared__ float mu_s, rs_s;
    int wv = tid >> 6, lane = tid & 63;
    if (lane == 0) { ps[wv] = s; ps2[wv] = s2; }
    __syncthreads();
    if (tid == 0) {
        float st  = ps[0] + ps[1] + ps[2] + ps[3];
        float st2 = ps2[0] + ps2[1] + ps2[2] + ps2[3];
        float mu = st / (float)CC;
        float var = st2 / (float)CC - mu * mu;
        mu_s = mu; rs_s = rsqrtf(var + 1e-5f);
    }
    __syncthreads();
    float mu = mu_s, rs = rs_s;
    float4 gv = *(const float4*)(g + tid * 4);
    float4 bv = *(const float4*)(bta + tid * 4);
    u16 o0 = f2bf((v.x - mu) * rs * gv.x + bv.x);
    u16 o1 = f2bf((v.y - mu) * rs * gv.y + bv.y);
    u16 o2 = f2bf((v.z - mu) * rs * gv.z + bv.z);
    u16 o3 = f2bf((v.w - mu) * rs * gv.w + bv.w);
    uint2 pk;
    pk.x = (unsigned)o0 | ((unsigned)o1 << 16);
    pk.y = (unsigned)o2 | ((unsigned)o3 << 16);
    *(uint2*)(out + (size_t)row * CC + tid * 4) = pk;
}

// ---------- generic NT GEMM: A bf16[M,K] @ Bt bf16[N,K] ----------
// EPI 0: qkv scatter (bf16 into q/k/v layouts) | EPI 1: +bias+resid -> f32 out
// EPI 2: +bias, exact GELU -> bf16 out
template<int EPI>
__global__ __launch_bounds__(256, 2)
void gemm_kernel(const u16* __restrict__ A, int lda,
                 const u16* __restrict__ Bt, int ldb,
                 const float* __restrict__ bias,
                 const float* __restrict__ resid,
                 void* __restrict__ out,
                 u16* __restrict__ qp, u16* __restrict__ kp, u16* __restrict__ vp,
                 int N, int K) {
    __shared__ u16 As[128 * 72];
    __shared__ u16 Bs[128 * 72];
    const int tid = threadIdx.x;
    const int wv = tid >> 6, lane = tid & 63;
    const int ln = lane & 15, q4 = lane >> 4;
    const int m_blk = blockIdx.y * 128, n_blk = blockIdx.x * 128;
    const int wr = (wv >> 1) * 64, wc = (wv & 1) * 64;

    f32x4 acc[4][4];
    #pragma unroll
    for (int i = 0; i < 4; i++)
        #pragma unroll
        for (int j = 0; j < 4; j++) acc[i][j] = (f32x4){0.f, 0.f, 0.f, 0.f};

    for (int kb = 0; kb < K; kb += 64) {
        uint4 ra[4], rb[4];
        #pragma unroll
        for (int i = 0; i < 4; i++) {
            int c = tid + 256 * i;
            int row = c >> 3, c8 = c & 7;
            ra[i] = *(const uint4*)(A  + (size_t)(m_blk + row) * lda + kb + c8 * 8);
            rb[i] = *(const uint4*)(Bt + (size_t)(n_blk + row) * ldb + kb + c8 * 8);
        }
        __syncthreads();
        #pragma unroll
        for (int i = 0; i < 4; i++) {
            int c = tid + 256 * i;
            int row = c >> 3, c8 = c & 7;
            *(uint4*)(As + row * 72 + c8 * 8) = ra[i];
            *(uint4*)(Bs + row * 72 + c8 * 8) = rb[i];
        }
        __syncthreads();
        #pragma unroll
        for (int kk = 0; kk < 2; kk++) {
            bf16x8 af[4], bfr[4];
            #pragma unroll
            for (int i = 0; i < 4; i++)
                af[i] = *(const bf16x8*)(As + (wr + 16*i + ln) * 72 + kk*32 + q4*8);
            #pragma unroll
            for (int j = 0; j < 4; j++)
                bfr[j] = *(const bf16x8*)(Bs + (wc + 16*j + ln) * 72 + kk*32 + q4*8);
            #pragma unroll
            for (int i = 0; i < 4; i++)
                #pragma unroll
                for (int j = 0; j < 4; j++)
                    acc[i][j] = mfma16(af[i], bfr[j], acc[i][j]);
        }
    }

    #pragma unroll
    for (int i = 0; i < 4; i++) {
        #pragma unroll
        for (int j = 0; j < 4; j++) {
            #pragma unroll
            for (int r = 0; r < 4; r++) {
                int row = m_blk + wr + 16*i + 4*q4 + r;   // C/D: row = 4*(lane>>4)+reg
                int col = n_blk + wc + 16*j + ln;         // C/D: col = lane&15
                float v = acc[i][j][r] + bias[col];
                if (EPI == 0) {
                    int region = col >> 10;
                    int cw = col & 1023;
                    int hd = cw >> 6, dh = cw & 63;
                    int b = row >> 11, t = row & 2047;
                    u16 bvv = f2bf(v);
                    size_t bhh = (size_t)(b * HH + hd);
                    if (region == 0)      qp[(bhh * TT + t) * DHD + dh] = bvv;
                    else if (region == 1) kp[(bhh * TT + t) * DHD + dh] = bvv;
                    else                  vp[(bhh * DHD + dh) * TT + t] = bvv;
                } else if (EPI == 1) {
                    ((float*)out)[(size_t)row * N + col] = v + resid[(size_t)row * N + col];
                } else {
                    float gl = 0.5f * v * (1.0f + erff(v * 0.70710678118654752f));
                    ((u16*)out)[(size_t)row * N + col] = f2bf(gl);
                }
            }
        }
    }
}

// ---------- fused causal attention, writes att (f32) + y (bf16 [B,T,C]) ----------
__global__ __launch_bounds__(256, 1)
void attn_kernel(const u16* __restrict__ q_ws, const u16* __restrict__ k_ws,
                 const u16* __restrict__ v_ws, float* __restrict__ att_out,
                 u16* __restrict__ y_ws) {
    __shared__ u16 Qs[128 * 72];
    __shared__ u16 Ks[64 * 72];
    __shared__ u16 Vs[64 * 72];
    __shared__ u16 Ps[128 * 72];
    const int tid = threadIdx.x;
    const int wv = tid >> 6, lane = tid & 63;
    const int ln = lane & 15, q4 = lane >> 4;
    const int bh = blockIdx.x;   // b*16+h
    const int qt = blockIdx.y;   // q tile of 128
    const int bb = bh >> 4, hd = bh & 15;

    const u16* Qg = q_ws + ((size_t)bh * TT + qt * 128) * DHD;
    const u16* Kg = k_ws + (size_t)bh * TT * DHD;
    const u16* Vg = v_ws + (size_t)bh * DHD * TT;   // [DH][T]
    float* att = att_out + (size_t)bh * TT * TT + (size_t)(qt * 128) * TT;

    // zero-fill columns >= (qt+1)*128 for our 128 rows (never-visited blocks)
    {
        int zstart = (qt + 1) * 128;
        int zc = TT - zstart;
        int cpr = zc >> 2;
        int tot4 = 128 * cpr;
        for (int v = tid; v < tot4; v += 256) {
            int row = v / (cpr > 0 ? cpr : 1);
            int cv = v - row * cpr;
            *(f32x4*)(att + (size_t)row * TT + zstart + cv * 4) = (f32x4){0.f,0.f,0.f,0.f};
        }
    }

    // load Q tile
    #pragma unroll
    for (int i = 0; i < 4; i++) {
        int c = tid + 256 * i;
        int row = c >> 3, c8 = c & 7;
        *(uint4*)(Qs + row * 72 + c8 * 8) = *(const uint4*)(Qg + (size_t)row * DHD + c8 * 8);
    }

    float m_run[2][4], l_run[2][4];
    #pragma unroll
    for (int rt = 0; rt < 2; rt++)
        #pragma unroll
        for (int r = 0; r < 4; r++) { m_run[rt][r] = -1e30f; l_run[rt][r] = 0.f; }

    const int nkt = 2 * qt + 2;   // k tiles of 64
    const float scale = 0.125f;   // 1/sqrt(64)

    // ---- PASS 1: streaming max/sum ----
    for (int kt = 0; kt < nkt; kt++) {
        __syncthreads();
        #pragma unroll
        for (int i = 0; i < 2; i++) {
            int c = tid + 256 * i;
            int row = c >> 3, c8 = c & 7;
            *(uint4*)(Ks + row * 72 + c8 * 8) =
                *(const uint4*)(Kg + (size_t)(kt * 64 + row) * DHD + c8 * 8);
        }
        __syncthreads();
        float sc[2][4][4];
        #pragma unroll
        for (int rt = 0; rt < 2; rt++) {
            bf16x8 a0 = *(const bf16x8*)(Qs + (32*wv + 16*rt + ln) * 72 + q4*8);
            bf16x8 a1 = *(const bf16x8*)(Qs + (32*wv + 16*rt + ln) * 72 + 32 + q4*8);
            #pragma unroll
            for (int ct = 0; ct < 4; ct++) {
                f32x4 s = (f32x4){0.f,0.f,0.f,0.f};
                bf16x8 b0 = *(const bf16x8*)(Ks + (16*ct + ln) * 72 + q4*8);
                bf16x8 b1 = *(const bf16x8*)(Ks + (16*ct + ln) * 72 + 32 + q4*8);
                s = mfma16(a0, b0, s);
                s = mfma16(a1, b1, s);
                #pragma unroll
                for (int r = 0; r < 4; r++) {
                    int rowg = qt * 128 + 32*wv + 16*rt + 4*q4 + r;
                    int colg = kt * 64 + 16*ct + ln;
                    sc[rt][ct][r] = (colg <= rowg) ? s[r] * scale : -1e30f;
                }
            }
        }
        #pragma unroll
        for (int rt = 0; rt < 2; rt++)
            #pragma unroll
            for (int r = 0; r < 4; r++) {
                float tmax = fmaxf(fmaxf(sc[rt][0][r], sc[rt][1][r]),
                                   fmaxf(sc[rt][2][r], sc[rt][3][r]));
                for (int o = 1; o < 16; o <<= 1) tmax = fmaxf(tmax, __shfl_xor(tmax, o, 64));
                float nm = fmaxf(m_run[rt][r], tmax);
                float ps = 0.f;
                #pragma unroll
                for (int ct = 0; ct < 4; ct++) ps += __expf(sc[rt][ct][r] - nm);
                for (int o = 1; o < 16; o <<= 1) ps += __shfl_xor(ps, o, 64);
                l_run[rt][r] = l_run[rt][r] * __expf(m_run[rt][r] - nm) + ps;
                m_run[rt][r] = nm;
            }
    }
    float inv_l[2][4];
    #pragma unroll
    for (int rt = 0; rt < 2; rt++)
        #pragma unroll
        for (int r = 0; r < 4; r++) inv_l[rt][r] = 1.0f / l_run[rt][r];

    f32x4 acc_y[2][4];
    #pragma unroll
    for (int rt = 0; rt < 2; rt++)
        #pragma unroll
        for (int j = 0; j < 4; j++) acc_y[rt][j] = (f32x4){0.f,0.f,0.f,0.f};

    // ---- PASS 2: recompute with final (m,l), write att, accumulate y ----
    for (int kt = 0; kt < nkt; kt++) {
        __syncthreads();
        #pragma unroll
        for (int i = 0; i < 2; i++) {
            int c = tid + 256 * i;
            int row = c >> 3, c8 = c & 7;
            *(uint4*)(Ks + row * 72 + c8 * 8) =
                *(const uint4*)(Kg + (size_t)(kt * 64 + row) * DHD + c8 * 8);
            *(uint4*)(Vs + row * 72 + c8 * 8) =
                *(const uint4*)(Vg + (size_t)row * TT + kt * 64 + c8 * 8);
        }
        __syncthreads();
        #pragma unroll
        for (int rt = 0; rt < 2; rt++) {
            bf16x8 a0 = *(const bf16x8*)(Qs + (32*wv + 16*rt + ln) * 72 + q4*8);
            bf16x8 a1 = *(const bf16x8*)(Qs + (32*wv + 16*rt + ln) * 72 + 32 + q4*8);
            #pragma unroll
            for (int ct = 0; ct < 4; ct++) {
                f32x4 s = (f32x4){0.f,0.f,0.f,0.f};
                bf16x8 b0 = *(const bf16x8*)(Ks + (16*ct + ln) * 72 + q4*8);
                bf16x8 b1 = *(const bf16x8*)(Ks + (16*ct + ln) * 72 + 32 + q4*8);
                s = mfma16(a0, b0, s);
                s = mfma16(a1, b1, s);
                #pragma unroll
                for (int r = 0; r < 4; r++) {
                    int rowl = 32*wv + 16*rt + 4*q4 + r;
                    int rowg = qt * 128 + rowl;
                    int colg = kt * 64 + 16*ct + ln;
                    float p = (colg <= rowg)
                            ? __expf(s[r] * scale - m_run[rt][r]) * inv_l[rt][r] : 0.f;
                    att[(size_t)rowl * TT + colg] = p;
                    Ps[rowl * 72 + 16*ct + ln] = f2bf(p);
                }
            }
        }
        __syncthreads();
        #pragma unroll
        for (int kk = 0; kk < 2; kk++) {
            bf16x8 pa[2], vb[4];
            #pragma unroll
            for (int rt = 0; rt < 2; rt++)
                pa[rt] = *(const bf16x8*)(Ps + (32*wv + 16*rt + ln) * 72 + kk*32 + q4*8);
            #pragma unroll
            for (int j = 0; j < 4; j++)
                vb[j] = *(const bf16x8*)(Vs + (16*j + ln) * 72 + kk*32 + q4*8);
            #pragma unroll
            for (int rt = 0; rt < 2; rt++)
                #pragma unroll
                for (int j = 0; j < 4; j++)
                    acc_y[rt][j] = mfma16(pa[rt], vb[j], acc_y[rt][j]);
        }
    }

    // y epilogue -> y_ws [B,T,C] at col h*64+dh
    #pragma unroll
    for (int rt = 0; rt < 2; rt++)
        #pragma unroll
        for (int j = 0; j < 4; j++)
            #pragma unroll
            for (int r = 0; r < 4; r++) {
                int rowl = 32*wv + 16*rt + 4*q4 + r;
                int t = qt * 128 + rowl;
                int dh = 16*j + ln;
                y_ws[((size_t)(bb * TT + t)) * CC + hd * DHD + dh] = f2bf(acc_y[rt][j][r]);
            }
}

// ---------- launch ----------
extern "C" void kernel_launch(void* const* d_in, const int* in_sizes, int n_in,
                              void* d_out, int out_size, void* d_ws, size_t ws_size,
                              hipStream_t stream) {
    const float* x      = (const float*)d_in[0];
    const float* W_attn = (const float*)d_in[1];
    const float* b_attn = (const float*)d_in[2];
    const float* W_o    = (const float*)d_in[3];
    const float* b_o    = (const float*)d_in[4];
    const float* W_fc   = (const float*)d_in[5];
    const float* b_fc   = (const float*)d_in[6];
    const float* W_fc2  = (const float*)d_in[7];
    const float* b_fc2  = (const float*)d_in[8];
    const float* g1     = (const float*)d_in[9];
    const float* beta1  = (const float*)d_in[10];
    const float* g2     = (const float*)d_in[11];
    const float* beta2  = (const float*)d_in[12];

    char* ws = (char*)d_ws;
    u16* Wt_attn = (u16*)(ws);             // [3072][1024]
    u16* Wt_o    = (u16*)(ws + 6291456);   // [1024][1024]
    u16* Wt_fc   = (u16*)(ws + 8388608);   // [4096][1024]
    u16* Wt_fc2  = (u16*)(ws + 16777216);  // [1024][4096]
    u16* h_ws    = (u16*)(ws + 25165824);  // [4096][1024] (h, then h2)
    u16* q_ws    = (u16*)(ws + 33554432);  // [B,H,T,DH]
    u16* k_ws    = (u16*)(ws + 41943040);  // [B,H,T,DH]
    u16* v_ws    = (u16*)(ws + 50331648);  // [B,H,DH,T]
    u16* y_ws    = (u16*)(ws + 58720256);  // [4096][1024]
    u16* m_ws    = (u16*)(ws + 33554432);  // [4096][4096] aliases q/k/v/y (dead)
    float* x1_ws = (float*)(ws + 67108864);// [4096][1024] f32

    float* out_x = (float*)d_out;
    float* att   = (float*)d_out + (size_t)BB * TT * CC;  // 4194304

    dim3 tb(32, 8);
    transpose_cast<<<dim3(3072/32, 1024/32), tb, 0, stream>>>(W_attn, Wt_attn, 1024, 3072);
    transpose_cast<<<dim3(1024/32, 1024/32), tb, 0, stream>>>(W_o,    Wt_o,    1024, 1024);
    transpose_cast<<<dim3(4096/32, 1024/32), tb, 0, stream>>>(W_fc,   Wt_fc,   1024, 4096);
    transpose_cast<<<dim3(1024/32, 4096/32), tb, 0, stream>>>(W_fc2,  Wt_fc2,  4096, 1024);

    ln_kernel<<<MM, 256, 0, stream>>>(x, g1, beta1, h_ws);

    gemm_kernel<0><<<dim3(3072/128, MM/128), 256, 0, stream>>>(
        h_ws, 1024, Wt_attn, 1024, b_attn, nullptr, nullptr, q_ws, k_ws, v_ws, 3072, 1024);

    attn_kernel<<<dim3(BB*HH, TT/128), 256, 0, stream>>>(q_ws, k_ws, v_ws, att, y_ws);

    gemm_kernel<1><<<dim3(1024/128, MM/128), 256, 0, stream>>>(
        y_ws, 1024, Wt_o, 1024, b_o, x, x1_ws, nullptr, nullptr, nullptr, 1024, 1024);

    ln_kernel<<<MM, 256, 0, stream>>>(x1_ws, g2, beta2, h_ws);

    gemm_kernel<2><<<dim3(4096/128, MM/128), 256, 0, stream>>>(
        h_ws, 1024, Wt_fc, 1024, b_fc, nullptr, m_ws, nullptr, nullptr, nullptr, 4096, 1024);

    gemm_kernel<1><<<dim3(1024/128, MM/128), 256, 0, stream>>>(
        m_ws, 4096, Wt_fc2, 4096, b_fc2, x1_ws, out_x, nullptr, nullptr, nullptr, 1024, 4096);
}

// Round 2
// 917.756 us; speedup vs baseline: 1.4433x; 1.4433x over previous
//
#include <hip/hip_runtime.h>
#include <math.h>

// ---------- problem constants ----------
#define BB  2
#define TT  2048
#define CC  1024
#define HH  16
#define DHD 64
#define MM  (BB*TT)        // 4096 rows

typedef unsigned short u16;
typedef __bf16 bf16t;
typedef bf16t bf16x8 __attribute__((ext_vector_type(8)));
typedef float f32x4 __attribute__((ext_vector_type(4)));

__device__ __forceinline__ u16 f2bf(float f) {
    union { float f; unsigned int u; } v; v.f = f;
    unsigned int r = v.u + 0x7fffu + ((v.u >> 16) & 1u);
    return (u16)(r >> 16);
}

__device__ __forceinline__ f32x4 mfma16(bf16x8 a, bf16x8 b, f32x4 c) {
    return __builtin_amdgcn_mfma_f32_16x16x32_bf16(a, b, c, 0, 0, 0);
}

// async global->LDS, 16B per lane (wave-uniform base + lane*16 on LDS side)
__device__ __forceinline__ void gload_lds16(const u16* g, u16* l) {
    __builtin_amdgcn_global_load_lds(
        (const __attribute__((address_space(1))) void*)g,
        (__attribute__((address_space(3))) void*)l, 16, 0, 0);
}

// ---------- transpose + cast f32[R][Cc] -> bf16[Cc][R] ----------
__global__ __launch_bounds__(256)
void transpose_cast(const float* __restrict__ in, u16* __restrict__ out, int R, int Cc) {
    __shared__ float tile[32][33];
    int tx = threadIdx.x, ty = threadIdx.y;
    int c0 = blockIdx.x * 32, r0 = blockIdx.y * 32;
    #pragma unroll
    for (int k = 0; k < 4; k++)
        tile[ty + 8*k][tx] = in[(size_t)(r0 + ty + 8*k) * Cc + c0 + tx];
    __syncthreads();
    #pragma unroll
    for (int k = 0; k < 4; k++)
        out[(size_t)(c0 + ty + 8*k) * R + r0 + tx] = f2bf(tile[tx][ty + 8*k]);
}

// ---------- V slice transpose: qkv[M][3072] v-region -> vt [B*H][DH][T] ----------
__global__ __launch_bounds__(256)
void vtrans(const u16* __restrict__ qkv, u16* __restrict__ vt) {
    __shared__ u16 tile[32][33];
    int bh = blockIdx.z, bb = bh >> 4, hd = bh & 15;
    int t0 = blockIdx.x * 32, d0 = blockIdx.y * 32;
    int tx = threadIdx.x, ty = threadIdx.y;
    #pragma unroll
    for (int k = 0; k < 4; k++)
        tile[ty + 8*k][tx] =
            qkv[(size_t)(bb * TT + t0 + ty + 8*k) * 3072 + 2048 + hd * 64 + d0 + tx];
    __syncthreads();
    #pragma unroll
    for (int k = 0; k < 4; k++)
        vt[((size_t)bh * 64 + d0 + ty + 8*k) * TT + t0 + tx] = tile[tx][ty + 8*k];
}

// ---------- LayerNorm: f32[rows][1024] -> bf16[rows][1024] ----------
__global__ __launch_bounds__(256)
void ln_kernel(const float* __restrict__ x, const float* __restrict__ g,
               const float* __restrict__ bta, u16* __restrict__ out) {
    const int row = blockIdx.x;
    const int tid = threadIdx.x;
    const float* xr = x + (size_t)row * CC;
    float4 v = *(const float4*)(xr + tid * 4);
    float s  = v.x + v.y + v.z + v.w;
    float s2 = v.x*v.x + v.y*v.y + v.z*v.z + v.w*v.w;
    for (int o = 32; o > 0; o >>= 1) {
        s  += __shfl_down(s,  o, 64);
        s2 += __shfl_down(s2, o, 64);
    }
    __shared__ float ps[4], ps2[4];
    __shared__ float mu_s, rs_s;
    int wv = tid >> 6, lane = tid & 63;
    if (lane == 0) { ps[wv] = s; ps2[wv] = s2; }
    __syncthreads();
    if (tid == 0) {
        float st  = ps[0] + ps[1] + ps[2] + ps[3];
        float st2 = ps2[0] + ps2[1] + ps2[2] + ps2[3];
        float mu = st / (float)CC;
        float var = st2 / (float)CC - mu * mu;
        mu_s = mu; rs_s = rsqrtf(var + 1e-5f);
    }
    __syncthreads();
    float mu = mu_s, rs = rs_s;
    float4 gv = *(const float4*)(g + tid * 4);
    float4 bv = *(const float4*)(bta + tid * 4);
    u16 o0 = f2bf((v.x - mu) * rs * gv.x + bv.x);
    u16 o1 = f2bf((v.y - mu) * rs * gv.y + bv.y);
    u16 o2 = f2bf((v.z - mu) * rs * gv.z + bv.z);
    u16 o3 = f2bf((v.w - mu) * rs * gv.w + bv.w);
    uint2 pk;
    pk.x = (unsigned)o0 | ((unsigned)o1 << 16);
    pk.y = (unsigned)o2 | ((unsigned)o3 << 16);
    *(uint2*)(out + (size_t)row * CC + tid * 4) = pk;
}

// ---------- m97-style NT GEMM: A bf16[M,K] @ Bt bf16[N,K], 128x128 tile ----------
// EPI 0: +bias -> bf16 out | EPI 1: +bias+resid -> f32 out | EPI 2: +bias, GELU -> bf16
template<int EPI>
__global__ __launch_bounds__(256, 2)
void gemm_kernel(const u16* __restrict__ A, int lda,
                 const u16* __restrict__ Bt, int ldb,
                 const float* __restrict__ bias,
                 const float* __restrict__ resid,
                 void* __restrict__ out, int N, int K) {
    __shared__ __align__(16) u16 As[128 * 64];
    __shared__ __align__(16) u16 Bs[128 * 64];
    const int tid = threadIdx.x;
    const int wv = tid >> 6, lane = tid & 63;
    const int ln = lane & 15, q4 = lane >> 4;
    const int l7 = ln & 7;
    const int sw0 = (q4 ^ l7) * 8;          // chunk pos for k-half 0
    const int sw1 = ((4 + q4) ^ l7) * 8;    // chunk pos for k-half 1
    const int m_blk = blockIdx.y * 128, n_blk = blockIdx.x * 128;
    const int wr = (wv >> 1) * 64, wc = (wv & 1) * 64;

    f32x4 acc[4][4];
    #pragma unroll
    for (int i = 0; i < 4; i++)
        #pragma unroll
        for (int j = 0; j < 4; j++) acc[i][j] = (f32x4){0.f, 0.f, 0.f, 0.f};

    for (int kb = 0; kb < K; kb += 64) {
        __syncthreads();
        #pragma unroll
        for (int it = 0; it < 4; it++) {
            int b = it * 256 + tid;
            int row = b >> 3, c = b & 7;
            int cg = c ^ (row & 7);
            gload_lds16(A  + (size_t)(m_blk + row) * lda + kb + cg * 8, As + b * 8);
            gload_lds16(Bt + (size_t)(n_blk + row) * ldb + kb + cg * 8, Bs + b * 8);
        }
        __syncthreads();
        #pragma unroll
        for (int kk = 0; kk < 2; kk++) {
            const int sw = kk ? sw1 : sw0;
            bf16x8 af[4], bfr[4];
            #pragma unroll
            for (int i = 0; i < 4; i++)
                af[i] = *(const bf16x8*)(As + (wr + 16*i + ln) * 64 + sw);
            #pragma unroll
            for (int j = 0; j < 4; j++)
                bfr[j] = *(const bf16x8*)(Bs + (wc + 16*j + ln) * 64 + sw);
            #pragma unroll
            for (int i = 0; i < 4; i++)
                #pragma unroll
                for (int j = 0; j < 4; j++)
                    acc[i][j] = mfma16(af[i], bfr[j], acc[i][j]);
        }
    }

    #pragma unroll
    for (int i = 0; i < 4; i++) {
        #pragma unroll
        for (int j = 0; j < 4; j++) {
            #pragma unroll
            for (int r = 0; r < 4; r++) {
                int row = m_blk + wr + 16*i + 4*q4 + r;   // C/D: row = 4*(lane>>4)+reg
                int col = n_blk + wc + 16*j + ln;         // C/D: col = lane&15
                float v = acc[i][j][r] + bias[col];
                if (EPI == 0) {
                    ((u16*)out)[(size_t)row * N + col] = f2bf(v);
                } else if (EPI == 1) {
                    ((float*)out)[(size_t)row * N + col] = v + resid[(size_t)row * N + col];
                } else {
                    float gl = 0.5f * v * (1.0f + erff(v * 0.70710678118654752f));
                    ((u16*)out)[(size_t)row * N + col] = f2bf(gl);
                }
            }
        }
    }
}

// ---------- fused causal attention ----------
// Q,K read from qkv [M][3072]; V from vt [B*H][64][T]; writes att f32 + y bf16 [B,T,C]
__global__ __launch_bounds__(256, 2)
void attn_kernel(const u16* __restrict__ qkv, const u16* __restrict__ vt,
                 float* __restrict__ att_out, u16* __restrict__ y_ws) {
    __shared__ __align__(16) u16 Qs[128 * 64];
    __shared__ __align__(16) u16 Ks[2][64 * 64];
    __shared__ __align__(16) u16 Vs[2][64 * 64];
    __shared__ __align__(16) u16 Ps[128 * 72];
    const int tid = threadIdx.x;
    const int wv = tid >> 6, lane = tid & 63;
    const int ln = lane & 15, q4 = lane >> 4;
    const int l7 = ln & 7;
    const int sw0 = (q4 ^ l7) * 8;
    const int sw1 = ((4 + q4) ^ l7) * 8;
    const int bx = blockIdx.x;
    // makespan balance: CU c gets qt and 15-qt
    const int qt = (bx < 256) ? (15 - (bx >> 5)) : ((bx - 256) >> 5);
    const int bh = bx & 31, bb = bh >> 4, hd = bh & 15;

    const u16* Qg = qkv + ((size_t)(bb * TT) + qt * 128) * 3072 + hd * 64;
    const u16* Kg = qkv + (size_t)(bb * TT) * 3072 + 1024 + hd * 64;
    const u16* Vg = vt + (size_t)bh * 64 * TT;
    float* att = att_out + (size_t)bh * TT * TT + (size_t)(qt * 128) * TT;

    // stage Q tile (async)
    #pragma unroll
    for (int it = 0; it < 4; it++) {
        int b = it * 256 + tid;
        int row = b >> 3, c = b & 7, cg = c ^ (row & 7);
        gload_lds16(Qg + (size_t)row * 3072 + cg * 8, Qs + b * 8);
    }
    // prologue K tile 0 (async)
    {
        #pragma unroll
        for (int it = 0; it < 2; it++) {
            int b = it * 256 + tid;
            int row = b >> 3, c = b & 7, cg = c ^ (row & 7);
            gload_lds16(Kg + (size_t)row * 3072 + cg * 8, Ks[0] + b * 8);
        }
    }
    // zero-fill never-visited att columns (overlaps the async loads)
    {
        int zstart = (qt + 1) * 128;
        int zc = TT - zstart;
        if (zc > 0) {
            int cpr = zc >> 2;
            int tot = 128 * cpr;
            for (int v = tid; v < tot; v += 256) {
                int row = v / cpr;
                int c4 = v - row * cpr;
                *(f32x4*)(att + (size_t)row * TT + zstart + c4 * 4) =
                    (f32x4){0.f, 0.f, 0.f, 0.f};
            }
        }
    }

    float m_run[2][4], l_run[2][4];
    #pragma unroll
    for (int rt = 0; rt < 2; rt++)
        #pragma unroll
        for (int r = 0; r < 4; r++) { m_run[rt][r] = -1e30f; l_run[rt][r] = 0.f; }

    const int nkt = 2 * qt + 2;
    const float scale = 0.125f;

    // ---- PASS 1: streaming (m,l); 1 barrier/iter, loads overlap compute ----
    for (int kt = 0; kt < nkt; kt++) {
        __syncthreads();   // drains async loads for tile kt
        if (kt + 1 < nkt) {
            u16* dst = Ks[(kt + 1) & 1];
            #pragma unroll
            for (int it = 0; it < 2; it++) {
                int b = it * 256 + tid;
                int row = b >> 3, c = b & 7, cg = c ^ (row & 7);
                gload_lds16(Kg + (size_t)((kt + 1) * 64 + row) * 3072 + cg * 8, dst + b * 8);
            }
        }
        const u16* Kb = Ks[kt & 1];
        float sc[2][4][4];
        #pragma unroll
        for (int rt = 0; rt < 2; rt++) {
            int qrow = (32*wv + 16*rt + ln);
            bf16x8 a0 = *(const bf16x8*)(Qs + qrow * 64 + sw0);
            bf16x8 a1 = *(const bf16x8*)(Qs + qrow * 64 + sw1);
            #pragma unroll
            for (int ct = 0; ct < 4; ct++) {
                int krow = 16*ct + ln;
                f32x4 s = (f32x4){0.f,0.f,0.f,0.f};
                bf16x8 b0 = *(const bf16x8*)(Kb + krow * 64 + sw0);
                bf16x8 b1 = *(const bf16x8*)(Kb + krow * 64 + sw1);
                s = mfma16(a0, b0, s);
                s = mfma16(a1, b1, s);
                #pragma unroll
                for (int r = 0; r < 4; r++) {
                    int rowg = qt * 128 + 32*wv + 16*rt + 4*q4 + r;
                    int colg = kt * 64 + 16*ct + ln;
                    sc[rt][ct][r] = (colg <= rowg) ? s[r] * scale : -1e30f;
                }
            }
        }
        #pragma unroll
        for (int rt = 0; rt < 2; rt++)
            #pragma unroll
            for (int r = 0; r < 4; r++) {
                float tmax = fmaxf(fmaxf(sc[rt][0][r], sc[rt][1][r]),
                                   fmaxf(sc[rt][2][r], sc[rt][3][r]));
                for (int o = 1; o < 16; o <<= 1) tmax = fmaxf(tmax, __shfl_xor(tmax, o, 64));
                float nm = fmaxf(m_run[rt][r], tmax);
                float psum = 0.f;
                #pragma unroll
                for (int ct = 0; ct < 4; ct++) psum += __expf(sc[rt][ct][r] - nm);
                for (int o = 1; o < 16; o <<= 1) psum += __shfl_xor(psum, o, 64);
                l_run[rt][r] = l_run[rt][r] * __expf(m_run[rt][r] - nm) + psum;
                m_run[rt][r] = nm;
            }
    }
    float inv_l[2][4];
    #pragma unroll
    for (int rt = 0; rt < 2; rt++)
        #pragma unroll
        for (int r = 0; r < 4; r++) inv_l[rt][r] = 1.0f / l_run[rt][r];

    f32x4 acc_y[2][4];
    #pragma unroll
    for (int rt = 0; rt < 2; rt++)
        #pragma unroll
        for (int j = 0; j < 4; j++) acc_y[rt][j] = (f32x4){0.f,0.f,0.f,0.f};

    // ---- PASS 2: recompute with final (m,l), write att, accumulate y ----
    __syncthreads();   // all waves done with pass-1 K buffers
    {
        #pragma unroll
        for (int it = 0; it < 2; it++) {
            int b = it * 256 + tid;
            int row = b >> 3, c = b & 7, cg = c ^ (row & 7);
            gload_lds16(Kg + (size_t)row * 3072 + cg * 8, Ks[0] + b * 8);
            gload_lds16(Vg + (size_t)row * TT + cg * 8,   Vs[0] + b * 8);
        }
    }
    for (int kt = 0; kt < nkt; kt++) {
        __syncthreads();   // (a) drains loads for tile kt
        if (kt + 1 < nkt) {
            u16* dk = Ks[(kt + 1) & 1];
            u16* dv = Vs[(kt + 1) & 1];
            #pragma unroll
            for (int it = 0; it < 2; it++) {
                int b = it * 256 + tid;
                int row = b >> 3, c = b & 7, cg = c ^ (row & 7);
                gload_lds16(Kg + (size_t)((kt + 1) * 64 + row) * 3072 + cg * 8, dk + b * 8);
                gload_lds16(Vg + (size_t)row * TT + (kt + 1) * 64 + cg * 8,     dv + b * 8);
            }
        }
        const u16* Kb = Ks[kt & 1];
        #pragma unroll
        for (int rt = 0; rt < 2; rt++) {
            int qrow = (32*wv + 16*rt + ln);
            bf16x8 a0 = *(const bf16x8*)(Qs + qrow * 64 + sw0);
            bf16x8 a1 = *(const bf16x8*)(Qs + qrow * 64 + sw1);
            #pragma unroll
            for (int ct = 0; ct < 4; ct++) {
                int krow = 16*ct + ln;
                f32x4 s = (f32x4){0.f,0.f,0.f,0.f};
                bf16x8 b0 = *(const bf16x8*)(Kb + krow * 64 + sw0);
                bf16x8 b1 = *(const bf16x8*)(Kb + krow * 64 + sw1);
                s = mfma16(a0, b0, s);
                s = mfma16(a1, b1, s);
                #pragma unroll
                for (int r = 0; r < 4; r++) {
                    int rowl = 32*wv + 16*rt + 4*q4 + r;
                    int rowg = qt * 128 + rowl;
                    int colg = kt * 64 + 16*ct + ln;
                    float p = (colg <= rowg)
                            ? __expf(s[r] * scale - m_run[rt][r]) * inv_l[rt][r] : 0.f;
                    att[(size_t)rowl * TT + colg] = p;
                    Ps[rowl * 72 + 16*ct + ln] = f2bf(p);
                }
            }
        }
        __syncthreads();   // (d) Ps ready
        const u16* Vb = Vs[kt & 1];
        #pragma unroll
        for (int kk = 0; kk < 2; kk++) {
            const int sw = kk ? sw1 : sw0;
            bf16x8 pa[2], vb[4];
            #pragma unroll
            for (int rt = 0; rt < 2; rt++)
                pa[rt] = *(const bf16x8*)(Ps + (32*wv + 16*rt + ln) * 72 + kk*32 + q4*8);
            #pragma unroll
            for (int j = 0; j < 4; j++)
                vb[j] = *(const bf16x8*)(Vb + (16*j + ln) * 64 + sw);
            #pragma unroll
            for (int rt = 0; rt < 2; rt++)
                #pragma unroll
                for (int j = 0; j < 4; j++)
                    acc_y[rt][j] = mfma16(pa[rt], vb[j], acc_y[rt][j]);
        }
    }

    // y epilogue -> y_ws [B,T,C] at col h*64+dh
    #pragma unroll
    for (int rt = 0; rt < 2; rt++)
        #pragma unroll
        for (int j = 0; j < 4; j++)
            #pragma unroll
            for (int r = 0; r < 4; r++) {
                int rowl = 32*wv + 16*rt + 4*q4 + r;
                int t = qt * 128 + rowl;
                int dh = 16*j + ln;
                y_ws[((size_t)(bb * TT + t)) * CC + hd * DHD + dh] = f2bf(acc_y[rt][j][r]);
            }
}

// ---------- launch ----------
extern "C" void kernel_launch(void* const* d_in, const int* in_sizes, int n_in,
                              void* d_out, int out_size, void* d_ws, size_t ws_size,
                              hipStream_t stream) {
    const float* x      = (const float*)d_in[0];
    const float* W_attn = (const float*)d_in[1];
    const float* b_attn = (const float*)d_in[2];
    const float* W_o    = (const float*)d_in[3];
    const float* b_o    = (const float*)d_in[4];
    const float* W_fc   = (const float*)d_in[5];
    const float* b_fc   = (const float*)d_in[6];
    const float* W_fc2  = (const float*)d_in[7];
    const float* b_fc2  = (const float*)d_in[8];
    const float* g1     = (const float*)d_in[9];
    const float* beta1  = (const float*)d_in[10];
    const float* g2     = (const float*)d_in[11];
    const float* beta2  = (const float*)d_in[12];

    char* ws = (char*)d_ws;
    u16* Wt_attn = (u16*)(ws);              // [3072][1024] bf16, 6 MB
    u16* Wt_o    = (u16*)(ws + 6291456);    // [1024][1024] 2 MB
    u16* Wt_fc   = (u16*)(ws + 8388608);    // [4096][1024] 8 MB
    u16* Wt_fc2  = (u16*)(ws + 16777216);   // [1024][4096] 8 MB
    u16* h_ws    = (u16*)(ws + 25165824);   // [4096][1024] 8 MB
    u16* qkv_ws  = (u16*)(ws + 33554432);   // [4096][3072] 24 MB
    u16* vt_ws   = (u16*)(ws + 58720256);   // [B*H][64][2048] 8 MB
    u16* y_ws    = (u16*)(ws + 67108864);   // [4096][1024] 8 MB  (end 75497472)
    u16* m_ws    = (u16*)(ws + 33554432);   // [4096][4096] 32 MB, aliases qkv+vt (dead)

    float* out_x = (float*)d_out;                          // [B,T,C] f32, doubles as x1
    float* att   = (float*)d_out + (size_t)BB * TT * CC;

    dim3 tb(32, 8);
    transpose_cast<<<dim3(3072/32, 1024/32), tb, 0, stream>>>(W_attn, Wt_attn, 1024, 3072);
    transpose_cast<<<dim3(1024/32, 1024/32), tb, 0, stream>>>(W_o,    Wt_o,    1024, 1024);
    transpose_cast<<<dim3(4096/32, 1024/32), tb, 0, stream>>>(W_fc,   Wt_fc,   1024, 4096);
    transpose_cast<<<dim3(1024/32, 4096/32), tb, 0, stream>>>(W_fc2,  Wt_fc2,  4096, 1024);

    ln_kernel<<<MM, 256, 0, stream>>>(x, g1, beta1, h_ws);

    gemm_kernel<0><<<dim3(3072/128, MM/128), 256, 0, stream>>>(
        h_ws, 1024, Wt_attn, 1024, b_attn, nullptr, qkv_ws, 3072, 1024);

    vtrans<<<dim3(TT/32, 2, BB*HH), tb, 0, stream>>>(qkv_ws, vt_ws);

    attn_kernel<<<dim3(512), 256, 0, stream>>>(qkv_ws, vt_ws, att, y_ws);

    gemm_kernel<1><<<dim3(1024/128, MM/128), 256, 0, stream>>>(
        y_ws, 1024, Wt_o, 1024, b_o, x, out_x, 1024, 1024);

    ln_kernel<<<MM, 256, 0, stream>>>(out_x, g2, beta2, h_ws);

    gemm_kernel<2><<<dim3(4096/128, MM/128), 256, 0, stream>>>(
        h_ws, 1024, Wt_fc, 1024, b_fc, nullptr, m_ws, 4096, 1024);

    gemm_kernel<1><<<dim3(1024/128, MM/128), 256, 0, stream>>>(
        m_ws, 4096, Wt_fc2, 4096, b_fc2, out_x, out_x, 1024, 4096);
}